// Round 3
// baseline (1570.014 us; speedup 1.0000x reference)
//
#include <hip/hip_runtime.h>
#include <hip/hip_bf16.h>

// RecurrentLayer: h <- 0.5h + 0.5(relu(h) W_hid^T + proj + noise)
// Two-kernel scheme:
//  1) proj_kernel: proj = x W_in^T written into d_out[s][b][g] (scan reads
//     its own slice as proj then overwrites with h[s] -- same-wave RAW).
//  2) scan_kernel: 8 chains (16 batch rows) x 2 WGs (256 g-cols, 8 waves).
//     Intra-WG h exchange via XOR-swizzled double-buffered LDS with raw
//     s_barrier+lgkmcnt (no vmcnt drain). Only the remote 8KB half crosses
//     MALL: wave w polls ONE 16B/lane chunk of the peer WG (bf16 sign-bit
//     period-2 step tag, 4-periodic with buffer parity -> stale-proof),
//     detags, ds_writes it for its siblings.

#define SEQ 512
#define NB  128
#define NI  128
#define NH  512

typedef __attribute__((ext_vector_type(8))) short  short8;
typedef __attribute__((ext_vector_type(4))) float  float4v;
typedef __attribute__((ext_vector_type(4))) int    int4v;
typedef __attribute__((ext_vector_type(2))) int    int2v;

#define SWZ(b, cb) ((cb) ^ (((b) & 7) << 4))

static __device__ __forceinline__ unsigned short f2bf(float f) {
    __hip_bfloat16 h = __float2bfloat16(f);
    unsigned short u;
    __builtin_memcpy(&u, &h, 2);
    return u;
}

static __device__ __forceinline__ short8 pack8(float4v a, float4v b) {
    short8 r;
    r[0] = (short)f2bf(a[0]); r[1] = (short)f2bf(a[1]);
    r[2] = (short)f2bf(a[2]); r[3] = (short)f2bf(a[3]);
    r[4] = (short)f2bf(b[0]); r[5] = (short)f2bf(b[1]);
    r[6] = (short)f2bf(b[2]); r[7] = (short)f2bf(b[3]);
    return r;
}

// raw barrier: LDS ops only (NO vmcnt drain -- publish stores stay in flight)
#define BARLDS() do { \
    asm volatile("s_waitcnt lgkmcnt(0)" ::: "memory"); \
    asm volatile("s_barrier" ::: "memory"); } while (0)

// ---------------- kernel 1: proj = x W_in^T -> out[s][b][g] ----------------
__global__ __launch_bounds__(256) void proj_kernel(
    const float* __restrict__ xin,   // [SEQ][NB][NI]
    const float* __restrict__ w_in,  // [NH][NI]
    float*       __restrict__ out)   // [SEQ][NB][NH] (proj region)
{
    const int lane = threadIdx.x & 63;
    const int wv   = threadIdx.x >> 6;           // 0..3
    const int r16  = lane & 15;
    const int kg   = lane >> 4;
    const int rt   = blockIdx.x;                 // 0..4095 row-tiles (16 rows)
    const int g0   = blockIdx.y * 128 + wv * 32; // g tile base

    short8 wfin[2][4];
#pragma unroll
    for (int t = 0; t < 2; ++t)
#pragma unroll
        for (int c = 0; c < 4; ++c) {
            const float* p = w_in + (size_t)(g0 + t * 16 + r16) * NI + c * 32 + kg * 8;
            wfin[t][c] = pack8(*(const float4v*)p, *(const float4v*)(p + 4));
        }
    const float* xp = xin + (size_t)(rt * 16 + r16) * NI + kg * 8;
    short8 bin[4];
#pragma unroll
    for (int c = 0; c < 4; ++c)
        bin[c] = pack8(*(const float4v*)(xp + c * 32), *(const float4v*)(xp + c * 32 + 4));

    float4v a0 = {0.f, 0.f, 0.f, 0.f};
    float4v a1 = {0.f, 0.f, 0.f, 0.f};
#pragma unroll
    for (int c = 0; c < 4; ++c) {
        a0 = __builtin_amdgcn_mfma_f32_16x16x32_bf16(wfin[0][c], bin[c], a0, 0, 0, 0);
        a1 = __builtin_amdgcn_mfma_f32_16x16x32_bf16(wfin[1][c], bin[c], a1, 0, 0, 0);
    }
    float* op = out + (size_t)(rt * 16 + r16) * NH + g0 + kg * 4;
    *(float4v*)op        = a0;
    *(float4v*)(op + 16) = a1;
}

// ---------------- kernel 2: persistent scan ----------------
// grid = 16 WGs x 512 thr: chain = bid&7, half H = bid>>3.
__global__ __launch_bounds__(512, 2) void scan_kernel(
    const float* __restrict__ w_hid,  // [NH][NH]
    const float* __restrict__ noise,  // [SEQ][NH]
    float*       __restrict__ out,    // [SEQ][NB][NH] (+ tail [NB][NH])
    unsigned short* __restrict__ gbuf) // 2 bufs x 16 slices x 8KB = 256KB
{
    __shared__ char lds_raw[32768];   // 2 x [16 b][512 h] bf16, XOR-swizzled
    char* lds = lds_raw;

    const int lane  = threadIdx.x & 63;
    const int wv    = threadIdx.x >> 6;       // 0..7
    const int r16   = lane & 15;
    const int kg    = lane >> 4;
    const int chain = blockIdx.x & 7;
    const int H     = blockIdx.x >> 3;        // 0/1
    const int b0    = chain * 16;
    const int g0    = H * 256 + wv * 32;
    const int cLoc  = H * 8;                  // local chunk base (chunk = 32 h)
    const int cRem  = (1 - H) * 8;

    // register-resident W_hid fragments, split local/remote K-halves so all
    // register-array indices are compile-time constants.
    short8 wfL[2][8], wfR[2][8];
#pragma unroll
    for (int t = 0; t < 2; ++t)
#pragma unroll
        for (int j = 0; j < 8; ++j) {
            const float* pL = w_hid + (size_t)(g0 + t * 16 + r16) * NH + (cLoc + j) * 32 + kg * 8;
            const float* pR = w_hid + (size_t)(g0 + t * 16 + r16) * NH + (cRem + j) * 32 + kg * 8;
            wfL[t][j] = pack8(*(const float4v*)pL, *(const float4v*)(pL + 4));
            wfR[t][j] = pack8(*(const float4v*)pR, *(const float4v*)(pR + 4));
        }

    float4v h0 = {0.f, 0.f, 0.f, 0.f};
    float4v h1 = {0.f, 0.f, 0.f, 0.f};

    const float* nzbase = noise + g0 + kg * 4;                       // + s*NH
    float*       outrow = out + (size_t)(b0 + r16) * NH + g0 + kg * 4; // + s*NB*NH

    // prefetch proj[0]/noise[0]
    float4v pfp0 = *(const float4v*)outrow;
    float4v pfp1 = *(const float4v*)(outrow + 16);
    float4v pfn0 = *(const float4v*)nzbase;
    float4v pfn1 = *(const float4v*)(nzbase + 16);

    const unsigned long long gb = (unsigned long long)(uintptr_t)gbuf;
    const unsigned long long myoff =
        (unsigned long long)(chain * 2 + H) * 8192ull + (unsigned)(r16 * 512 + wv * 64 + kg * 8);
    const unsigned long long peoff =
        (unsigned long long)(chain * 2 + (1 - H)) * 8192ull + (unsigned)(r16 * 512 + wv * 64 + kg * 16);
    const int rdrow = r16 * 1024;  // LDS row byte offset

#pragma unroll 1
    for (int s = 0; s < SEQ; ++s) {
        const float4v prj0 = pfp0, prj1 = pfp1, nz0 = pfn0, nz1 = pfn1;
        float4v p0a = {0.f,0.f,0.f,0.f}, p0b = {0.f,0.f,0.f,0.f};
        float4v p1a = {0.f,0.f,0.f,0.f}, p1b = {0.f,0.f,0.f,0.f};
        const int pb = (s - 1) & 1;

        if (s > 0) {
            // phase 1+2: local-half ds_reads + MFMAs (overlap remote flight)
            int4v rb[8];
#pragma unroll
            for (int j = 0; j < 8; ++j)
                rb[j] = *(const int4v*)(lds + pb * 16384 + rdrow +
                                        SWZ(r16, (cLoc + j) * 64 + kg * 16));
#pragma unroll
            for (int j = 0; j < 4; ++j) {
                short8 v = __builtin_bit_cast(short8, rb[j]);
                p0a = __builtin_amdgcn_mfma_f32_16x16x32_bf16(wfL[0][j], v, p0a, 0, 0, 0);
                p1a = __builtin_amdgcn_mfma_f32_16x16x32_bf16(wfL[1][j], v, p1a, 0, 0, 0);
            }
#pragma unroll
            for (int j = 4; j < 8; ++j) {
                short8 v = __builtin_bit_cast(short8, rb[j]);
                p0b = __builtin_amdgcn_mfma_f32_16x16x32_bf16(wfL[0][j], v, p0b, 0, 0, 0);
                p1b = __builtin_amdgcn_mfma_f32_16x16x32_bf16(wfL[1][j], v, p1b, 0, 0, 0);
            }
        }

        // prefetch proj/noise for s+1 (latency hides under poll / MFMA)
        if (s < SEQ - 1) {
            const float* orow = outrow + (size_t)(s + 1) * NB * NH;
            pfp0 = *(const float4v*)orow;
            pfp1 = *(const float4v*)(orow + 16);
            const float* nrow = nzbase + (size_t)(s + 1) * NH;
            pfn0 = *(const float4v*)nrow;
            pfn1 = *(const float4v*)(nrow + 16);
        }

        if (s > 0) {
            // phase 3: poll peer's chunk wv (16B/lane), tag = sign bits
            const unsigned expTag = ((unsigned)(s - 1) >> 1) & 1u;
            const unsigned long long pa = gb + (unsigned long long)pb * 131072ull + peoff;
            int4v rv;
            unsigned guard = 0;
            for (;;) {
                asm volatile("global_load_dwordx4 %0, %1, off sc0 sc1" : "=v"(rv) : "v"(pa));
                asm volatile("s_waitcnt vmcnt(0)" : "+v"(rv) :: "memory");
                bool ok;
                if (expTag)
                    ok = ((unsigned)(rv[0] & rv[1] & rv[2] & rv[3]) & 0x80008000u) == 0x80008000u;
                else
                    ok = ((unsigned)(rv[0] | rv[1] | rv[2] | rv[3]) & 0x80008000u) == 0u;
                if (__all(ok) || ++guard >= (1u << 14)) break;
            }
            __builtin_amdgcn_sched_barrier(0);
            if (expTag) {
                rv[0] &= 0x7FFF7FFF; rv[1] &= 0x7FFF7FFF;
                rv[2] &= 0x7FFF7FFF; rv[3] &= 0x7FFF7FFF;
            }
            // share with sibling waves via LDS
            *(int4v*)(lds + pb * 16384 + rdrow + SWZ(r16, (cRem + wv) * 64 + kg * 16)) = rv;
            BARLDS();  // B1: remote half complete

            // phase 5: remote-half ds_reads + MFMAs
            int4v rr[8];
#pragma unroll
            for (int j = 0; j < 8; ++j)
                rr[j] = *(const int4v*)(lds + pb * 16384 + rdrow +
                                        SWZ(r16, (cRem + j) * 64 + kg * 16));
#pragma unroll
            for (int j = 0; j < 4; ++j) {
                short8 v = __builtin_bit_cast(short8, rr[j]);
                p0a = __builtin_amdgcn_mfma_f32_16x16x32_bf16(wfR[0][j], v, p0a, 0, 0, 0);
                p1a = __builtin_amdgcn_mfma_f32_16x16x32_bf16(wfR[1][j], v, p1a, 0, 0, 0);
            }
#pragma unroll
            for (int j = 4; j < 8; ++j) {
                short8 v = __builtin_bit_cast(short8, rr[j]);
                p0b = __builtin_amdgcn_mfma_f32_16x16x32_bf16(wfR[0][j], v, p0b, 0, 0, 0);
                p1b = __builtin_amdgcn_mfma_f32_16x16x32_bf16(wfR[1][j], v, p1b, 0, 0, 0);
            }
        }

        // phase 6: state update
        float4v hn0, hn1;
#pragma unroll
        for (int r = 0; r < 4; ++r) {
            hn0[r] = 0.5f * h0[r] + 0.5f * (p0a[r] + p0b[r] + prj0[r] + nz0[r]);
            hn1[r] = 0.5f * h1[r] + 0.5f * (p1a[r] + p1b[r] + prj1[r] + nz1[r]);
        }
        h0 = hn0; h1 = hn1;

        // phase 7: pack relu(h) bf16 (untagged for LDS, tagged for global)
        unsigned u0 = (unsigned)f2bf(fmaxf(hn0[0], 0.f)) | ((unsigned)f2bf(fmaxf(hn0[1], 0.f)) << 16);
        unsigned u1 = (unsigned)f2bf(fmaxf(hn0[2], 0.f)) | ((unsigned)f2bf(fmaxf(hn0[3], 0.f)) << 16);
        unsigned u2 = (unsigned)f2bf(fmaxf(hn1[0], 0.f)) | ((unsigned)f2bf(fmaxf(hn1[1], 0.f)) << 16);
        unsigned u3 = (unsigned)f2bf(fmaxf(hn1[2], 0.f)) | ((unsigned)f2bf(fmaxf(hn1[3], 0.f)) << 16);
        const unsigned tm = ((s >> 1) & 1) ? 0x80008000u : 0u;
        int2v e0; e0[0] = (int)(u0 | tm); e0[1] = (int)(u1 | tm);
        int2v e1; e1[0] = (int)(u2 | tm); e1[1] = (int)(u3 | tm);
        const unsigned long long wb = gb + (unsigned long long)(s & 1) * 131072ull + myoff;
        asm volatile("global_store_dwordx2 %0, %1, off sc0 sc1" :: "v"(wb), "v"(e0) : "memory");
        asm volatile("global_store_dwordx2 %0, %1, off offset:32 sc0 sc1" :: "v"(wb), "v"(e1) : "memory");

        int2v l0; l0[0] = (int)u0; l0[1] = (int)u1;
        int2v l1; l1[0] = (int)u2; l1[1] = (int)u3;
        const int cb0 = H * 512 + wv * 64 + kg * 8;
        *(int2v*)(lds + (s & 1) * 16384 + rdrow + SWZ(r16, cb0))      = l0;
        *(int2v*)(lds + (s & 1) * 16384 + rdrow + SWZ(r16, cb0 + 32)) = l1;
        BARLDS();  // B2: local half of buf[s&1] complete

        // phase 9: output stores (off the sync path)
        float* op = outrow + (size_t)s * NB * NH;
        *(float4v*)op        = hn0;
        *(float4v*)(op + 16) = hn1;
        if (s == SEQ - 1) {
            float* tp = out + (size_t)SEQ * NB * NH + (size_t)(b0 + r16) * NH + g0 + kg * 4;
            *(float4v*)tp        = hn0;
            *(float4v*)(tp + 16) = hn1;
        }
    }
}

extern "C" void kernel_launch(void* const* d_in, const int* in_sizes, int n_in,
                              void* d_out, int out_size, void* d_ws, size_t ws_size,
                              hipStream_t stream) {
    (void)in_sizes; (void)n_in; (void)out_size; (void)ws_size;
    const float* xin   = (const float*)d_in[0];
    const float* w_in  = (const float*)d_in[1];
    const float* w_hid = (const float*)d_in[2];
    const float* noise = (const float*)d_in[3];
    float* out = (float*)d_out;

    unsigned short* gbuf = (unsigned short*)d_ws;  // 256 KB

    // poison 0xAA = sign bits set = tag 1; first uses expect tag 0.
    hipMemsetAsync(d_ws, 0xAA, 2 * 16 * 8192, stream);
    hipLaunchKernelGGL(proj_kernel, dim3(SEQ * NB / 16, 4), dim3(256), 0, stream,
                       xin, w_in, out);
    hipLaunchKernelGGL(scan_kernel, dim3(16), dim3(512), 0, stream,
                       w_hid, noise, out, gbuf);
}